// Round 13
// baseline (45.591 us; speedup 1.0000x reference)
//
#include <hip/hip_runtime.h>

// Problem constants (from reference setup_inputs)
#define BB 4
#define CC 128
#define HH 256
#define WW 256
#define NKP 4096
#define INV_RATIO (1.0f / 16.0f)
#define BAND 32               // rows per band
#define NBAND (HH / BAND)     // 8

typedef float fpair __attribute__((ext_vector_type(2)));
typedef float f4    __attribute__((ext_vector_type(4)));

// Loop inversion: instead of threads gathering at random addresses (scattered
// 8B reads capped at ~4.5 TB/s effective), each block OWNS a (batch, band,
// channel) slab and STREAMS it into LDS with sequential float4 loads (the
// same access pattern the harness fills run at 7.1 TB/s). Then it scans the
// batch's keypoint list (32KB, L2-resident after first touch) and processes
// the ~1/8 that land in its band out of LDS.
//
// Grid: BB * NBAND * CC = 4096 blocks of 256 threads. LDS 33KB -> 4 blocks/CU.
// Determinism: no atomics, no ws; each kp has exactly one band (via yp), so
// each output (b,c,n) is written exactly once by exactly one block.
__global__ __launch_bounds__(256) void interp_band_kernel(
    const float* __restrict__ feature,     // B x C x H x W
    const float* __restrict__ keypoints,   // B x N x 2
    float* __restrict__ out)               // B x C x N
{
    __shared__ float st[BAND + 1][WW];     // 33 rows x 256 cols = 33 KB

    int bid  = blockIdx.x;
    int c    = bid & (CC - 1);
    int band = (bid >> 7) & (NBAND - 1);
    int b    = bid >> 10;
    int tid  = threadIdx.x;
    int y0b  = band * BAND;

    // ---- stage rows y0b..y0b+31: 2048 float4s, fully sequential ----
    const f4* src = (const f4*)(feature + ((size_t)(b * CC + c) * HH + y0b) * WW);
    f4* dst = (f4*)&st[0][0];
    #pragma unroll
    for (int i = 0; i < 8; ++i)
        dst[tid + i * 256] = src[tid + i * 256];
    // halo row 32 <- min(y0b+32, 255) (for band 7 it's never read; safe dup)
    {
        int hy = min(y0b + BAND, HH - 1);
        const f4* hsrc = (const f4*)(feature + ((size_t)(b * CC + c) * HH + hy) * WW);
        if (tid < WW / 4) dst[(BAND * WW) / 4 + tid] = hsrc[tid];
    }
    __syncthreads();

    const float* kpb = keypoints + (size_t)b * NKP * 2;
    float* orow = out + (size_t)(b * CC + c) * NKP;

    // ---- scan all 4096 keypoints; process the ones in this band ----
    #pragma unroll 4
    for (int it = 0; it < NKP / 256; ++it) {   // 16 iterations
        int n = tid + it * 256;                // coalesced kp load
        fpair kpv;
        __builtin_memcpy(&kpv, kpb + 2 * (size_t)n, sizeof(fpair));
        float kx = kpv.x * INV_RATIO;
        float ky = kpv.y * INV_RATIO;

        float fy = fmaxf(floorf(ky), 0.0f);
        int y0 = (int)fy;
        int yp = (y0 >= HH - 1) ? (HH - 2) : y0;
        if ((yp >> 5) != band) continue;       // ~1/8 of lanes proceed

        float fx = fmaxf(floorf(kx), 0.0f);
        int x0 = (int)fx;

        float ux = kx - fx, uy = ky - fy;
        float lx = 1.0f - ux, ly = 1.0f - uy;

        bool selx = (x0 >= WW - 1);
        bool sely = (y0 >= HH - 1);
        int xp = selx ? (WW - 2) : x0;
        float wlx = selx ? 0.0f : lx, wux = selx ? 1.0f : ux;
        float wly = sely ? 0.0f : ly, wuy = sely ? 1.0f : uy;

        float mask = 0.5f * ((kx > 1e-10f ? 1.0f : 0.0f) + (ky > 1e-10f ? 1.0f : 0.0f));
        float w00 = wlx * wly * mask, w01 = wux * wly * mask;
        float w10 = wlx * wuy * mask, w11 = wux * wuy * mask;

        int yl = yp - y0b;                     // 0..31 (band7: <=30); yl+1 <= 32
        float v00 = st[yl][xp],     v01 = st[yl][xp + 1];
        float v10 = st[yl + 1][xp], v11 = st[yl + 1][xp + 1];

        orow[n] = w00 * v00 + w01 * v01 + w10 * v10 + w11 * v11;
    }
}

extern "C" void kernel_launch(void* const* d_in, const int* in_sizes, int n_in,
                              void* d_out, int out_size, void* d_ws, size_t ws_size,
                              hipStream_t stream) {
    const float* feature   = (const float*)d_in[0];
    const float* keypoints = (const float*)d_in[1];
    float* out = (float*)d_out;

    const int grid = BB * NBAND * CC;      // 4096
    interp_band_kernel<<<grid, 256, 0, stream>>>(feature, keypoints, out);
}

// Round 14
// 35.182 us; speedup vs baseline: 1.2959x; 1.2959x over previous
//
#include <hip/hip_runtime.h>

// Problem constants (from reference setup_inputs)
#define BB 4
#define CC 128
#define HH 256
#define WW 256
#define NKP 4096
#define INV_RATIO (1.0f / 16.0f)
#define BAND 32               // rows per band
#define NBAND (HH / BAND)     // 8
#define LCAP 1024             // list capacity per (b,band); mean 512, +24 sigma safe

typedef float fpair __attribute__((ext_vector_type(2)));
typedef float f4    __attribute__((ext_vector_type(4)));

// ws layout: lists  [BB*NBAND][LCAP] u32   (128 KB)
//            counts [BB*NBAND]       u32   (128 B)
#define O_CNT (BB * NBAND * LCAP * 4)
#define WS_NEEDED (O_CNT + BB * NBAND * 4)

// ---------- K1: bucket keypoints by y-band (one block per batch) ----------
__global__ __launch_bounds__(1024) void build_lists_kernel(
    const float* __restrict__ keypoints,   // B x N x 2
    unsigned* __restrict__ lists,          // BB*NBAND x LCAP
    unsigned* __restrict__ counts)         // BB*NBAND
{
    __shared__ unsigned cnt[NBAND];
    const int b = blockIdx.x;
    const int t = threadIdx.x;
    if (t < NBAND) cnt[t] = 0u;
    __syncthreads();

    #pragma unroll
    for (int k = 0; k < 4; ++k) {
        int n = t + 1024 * k;
        float ky = keypoints[((size_t)(b * NKP + n)) * 2 + 1] * INV_RATIO;
        int y0 = (int)fmaxf(floorf(ky), 0.0f);
        int yp = (y0 >= HH - 1) ? (HH - 2) : y0;
        int band = yp >> 5;                    // 0..7
        unsigned pos = atomicAdd(&cnt[band], 1u);
        if (pos < LCAP)
            lists[((b * NBAND + band) << 10) + pos] = (unsigned)n;
    }
    __syncthreads();
    if (t < NBAND) counts[b * NBAND + t] = min(cnt[t], (unsigned)LCAP);
}

// ---------- K2: stream band into LDS, process only its keypoints ----------
// Grid: BB * NBAND * CC = 4096 blocks of 256. LDS 33KB -> 4 blocks/CU.
// Each kp n belongs to exactly one band -> out(b,c,n) written exactly once.
// List order is race-dependent, but out[n] = f(kp[n], staged rows) is
// order-independent -> deterministic output.
__global__ __launch_bounds__(256) void interp_band_kernel(
    const float* __restrict__ feature,     // B x C x H x W
    const float* __restrict__ keypoints,   // B x N x 2
    const unsigned* __restrict__ lists,
    const unsigned* __restrict__ counts,
    float* __restrict__ out)               // B x C x N
{
    __shared__ float st[BAND + 1][WW];     // 33 KB

    int bid  = blockIdx.x;
    int c    = bid & (CC - 1);
    int band = (bid >> 7) & (NBAND - 1);
    int b    = bid >> 10;
    int tid  = threadIdx.x;
    int y0b  = band * BAND;

    // stage rows y0b..y0b+31 (32 KB sequential) + halo row
    const f4* src = (const f4*)(feature + ((size_t)(b * CC + c) * HH + y0b) * WW);
    f4* dst = (f4*)&st[0][0];
    #pragma unroll
    for (int i = 0; i < 8; ++i)
        dst[tid + i * 256] = src[tid + i * 256];
    {
        int hy = min(y0b + BAND, HH - 1);
        const f4* hsrc = (const f4*)(feature + ((size_t)(b * CC + c) * HH + hy) * WW);
        if (tid < WW / 4) dst[(BAND * WW) / 4 + tid] = hsrc[tid];
    }
    __syncthreads();

    const float* kpb = keypoints + (size_t)b * NKP * 2;
    float* orow = out + (size_t)(b * CC + c) * NKP;

    int cntv = (int)counts[b * NBAND + band];
    const unsigned* lst = lists + ((b * NBAND + band) << 10);

    for (int i = tid; i < cntv; i += 256) {
        unsigned n = lst[i];                    // coalesced list read (L2)
        fpair kpv;
        __builtin_memcpy(&kpv, kpb + 2 * (size_t)n, sizeof(fpair));  // L2 gather
        float kx = kpv.x * INV_RATIO;
        float ky = kpv.y * INV_RATIO;

        float fy = fmaxf(floorf(ky), 0.0f);
        int y0 = (int)fy;
        int yp = (y0 >= HH - 1) ? (HH - 2) : y0;

        float fx = fmaxf(floorf(kx), 0.0f);
        int x0 = (int)fx;

        float ux = kx - fx, uy = ky - fy;
        float lx = 1.0f - ux, ly = 1.0f - uy;

        bool selx = (x0 >= WW - 1);
        bool sely = (y0 >= HH - 1);
        int xp = selx ? (WW - 2) : x0;
        float wlx = selx ? 0.0f : lx, wux = selx ? 1.0f : ux;
        float wly = sely ? 0.0f : ly, wuy = sely ? 1.0f : uy;

        float mask = 0.5f * ((kx > 1e-10f ? 1.0f : 0.0f) + (ky > 1e-10f ? 1.0f : 0.0f));
        float w00 = wlx * wly * mask, w01 = wux * wly * mask;
        float w10 = wlx * wuy * mask, w11 = wux * wuy * mask;

        int yl = yp - y0b;                      // 0..31; yl+1 <= 32
        float v00 = st[yl][xp],     v01 = st[yl][xp + 1];
        float v10 = st[yl + 1][xp], v11 = st[yl + 1][xp + 1];

        orow[n] = w00 * v00 + w01 * v01 + w10 * v10 + w11 * v11;
    }
}

// ---------- Fallback: R8 direct gather (ws too small) ----------
#define CPT 4
#define NXCD 8
__global__ __launch_bounds__(256) void interp_direct_kernel(
    const float* __restrict__ feature,
    const float* __restrict__ keypoints,
    float* __restrict__ out)
{
    int bid   = blockIdx.x;
    int xcd   = bid & (NXCD - 1);
    int slot  = bid >> 3;
    int gloc  = slot >> 4;
    int j     = slot & 15;
    int g     = gloc * NXCD + xcd;
    int b     = g >> 5;
    int c0    = (g & 31) * CPT;
    int n     = j * 256 + threadIdx.x;

    const float* kp = keypoints + ((size_t)(b * NKP + n)) * 2;
    float kx = kp[0] * INV_RATIO;
    float ky = kp[1] * INV_RATIO;

    float fx = fmaxf(floorf(kx), 0.0f);
    float fy = fmaxf(floorf(ky), 0.0f);
    int x0 = (int)fx, y0 = (int)fy;

    float ux = kx - fx, uy = ky - fy;
    float lx = 1.0f - ux, ly = 1.0f - uy;

    bool selx = (x0 >= WW - 1);
    bool sely = (y0 >= HH - 1);
    int xp = selx ? (WW - 2) : x0;
    int yp = sely ? (HH - 2) : y0;
    float wlx = selx ? 0.0f : lx, wux = selx ? 1.0f : ux;
    float wly = sely ? 0.0f : ly, wuy = sely ? 1.0f : uy;

    float mask = 0.5f * ((kx > 1e-10f ? 1.0f : 0.0f) + (ky > 1e-10f ? 1.0f : 0.0f));
    float w00 = wlx * wly * mask, w01 = wux * wly * mask;
    float w10 = wlx * wuy * mask, w11 = wux * wuy * mask;

    int i0 = yp * WW + xp;
    int i1 = i0 + WW;

    const float* f = feature + ((size_t)(b * CC + c0)) * (HH * WW);

    fpair r0[CPT], r1[CPT];
    #pragma unroll
    for (int k = 0; k < CPT; ++k) {
        const float* fc = f + (size_t)k * (HH * WW);
        __builtin_memcpy(&r0[k], fc + i0, sizeof(fpair));
        __builtin_memcpy(&r1[k], fc + i1, sizeof(fpair));
    }

    float* o = out + ((size_t)(b * CC + c0)) * NKP + n;
    #pragma unroll
    for (int k = 0; k < CPT; ++k) {
        float val = w00 * r0[k].x + w01 * r0[k].y
                  + w10 * r1[k].x + w11 * r1[k].y;
        __builtin_nontemporal_store(val, o + (size_t)k * NKP);
    }
}

extern "C" void kernel_launch(void* const* d_in, const int* in_sizes, int n_in,
                              void* d_out, int out_size, void* d_ws, size_t ws_size,
                              hipStream_t stream) {
    const float* feature   = (const float*)d_in[0];
    const float* keypoints = (const float*)d_in[1];
    float* out = (float*)d_out;

    if (ws_size < WS_NEEDED) {
        interp_direct_kernel<<<BB * (CC / CPT) * (NKP / 256), 256, 0, stream>>>(
            feature, keypoints, out);
        return;
    }

    unsigned* lists  = (unsigned*)d_ws;
    unsigned* counts = (unsigned*)((char*)d_ws + O_CNT);

    build_lists_kernel<<<BB, 1024, 0, stream>>>(keypoints, lists, counts);
    interp_band_kernel<<<BB * NBAND * CC, 256, 0, stream>>>(
        feature, keypoints, lists, counts, out);
}

// Round 15
// 30.213 us; speedup vs baseline: 1.5090x; 1.1645x over previous
//
#include <hip/hip_runtime.h>

// Problem constants (from reference setup_inputs)
#define BB 4
#define CC 128
#define HH 256
#define WW 256
#define NKP 4096
#define INV_RATIO (1.0f / 16.0f)
#define CPT 4                 // channels per thread
#define NXCD 8

typedef float fpair __attribute__((ext_vector_type(2)));

// Grid: BB * (CC/CPT) * (NKP/256) = 2048 blocks of 256 threads.
// Swizzle: map-group g (= b*32 + c0/CPT) pinned to XCD g%8 (128 groups,
// 128%8==0 -> bijective). Each 4-map group (1 MB) is fetched into exactly
// one L2; keypoint line-reuse served from L2.
//
// Per (kp, channel) the two x-corners of each row are fetched with ONE
// 8-byte load (memcpy -> global_load_dwordx2, 4B-aligned OK on gfx950):
// 8.4M -> 4.2M scattered transactions vs the scalar version. Row-pair
// start clamped to W-2; the x0==W-1 (kx==255.0) case is folded into the
// x-weights (wlx=0, wux=1 -> picks pair.y with total weight lx+ux=1).
//
// Structural note (R7-R14 campaign): this kernel's ~30 us is set by the
// ~4.2M scattered 64B line-requests (~268 MB through L3->L2->L1 at the
// ~9 TB/s effective random-line rate). Sorted-order gather (R10),
// transposed mapping (R11), and streamed band staging (R13/R14) all
// landed at 32-46 us — the line-touch volume is compulsory and the
// request path, not HBM BW or instruction issue, is the wall.
__global__ __launch_bounds__(256) void interp_kernel(
    const float* __restrict__ feature,     // B x C x H x W
    const float* __restrict__ keypoints,   // B x N x 2
    float* __restrict__ out)               // B x C x N
{
    int bid   = blockIdx.x;        // 0..2047
    int xcd   = bid & (NXCD - 1);
    int slot  = bid >> 3;          // 0..255
    int gloc  = slot >> 4;         // 0..15
    int j     = slot & 15;         // 0..15
    int g     = gloc * NXCD + xcd; // 0..127
    int b     = g >> 5;
    int c0    = (g & 31) * CPT;
    int n     = j * 256 + threadIdx.x;

    const float* kp = keypoints + ((size_t)(b * NKP + n)) * 2;
    float kx = kp[0] * INV_RATIO;
    float ky = kp[1] * INV_RATIO;

    float fx = fmaxf(floorf(kx), 0.0f);
    float fy = fmaxf(floorf(ky), 0.0f);
    int x0 = (int)fx, y0 = (int)fy;

    float ux = kx - fx, uy = ky - fy;
    float lx = 1.0f - ux, ly = 1.0f - uy;

    // clamp pair start; fold boundary select into weights (once per kp)
    bool selx = (x0 >= WW - 1);
    bool sely = (y0 >= HH - 1);
    int xp = selx ? (WW - 2) : x0;
    int yp = sely ? (HH - 2) : y0;
    float wlx = selx ? 0.0f : lx, wux = selx ? 1.0f : ux;
    float wly = sely ? 0.0f : ly, wuy = sely ? 1.0f : uy;

    // mask folded into the 4 weights
    float mask = 0.5f * ((kx > 1e-10f ? 1.0f : 0.0f) + (ky > 1e-10f ? 1.0f : 0.0f));
    float w00 = wlx * wly * mask, w01 = wux * wly * mask;
    float w10 = wlx * wuy * mask, w11 = wux * wuy * mask;

    int i0 = yp * WW + xp;         // row y-lo pair
    int i1 = i0 + WW;              // row y-hi pair

    const float* f = feature + ((size_t)(b * CC + c0)) * (HH * WW);

    fpair r0[CPT], r1[CPT];
    #pragma unroll
    for (int k = 0; k < CPT; ++k) {
        const float* fc = f + (size_t)k * (HH * WW);
        __builtin_memcpy(&r0[k], fc + i0, sizeof(fpair));
        __builtin_memcpy(&r1[k], fc + i1, sizeof(fpair));
    }

    float* o = out + ((size_t)(b * CC + c0)) * NKP + n;
    #pragma unroll
    for (int k = 0; k < CPT; ++k) {
        float val = w00 * r0[k].x + w01 * r0[k].y
                  + w10 * r1[k].x + w11 * r1[k].y;
        __builtin_nontemporal_store(val, o + (size_t)k * NKP);
    }
}

extern "C" void kernel_launch(void* const* d_in, const int* in_sizes, int n_in,
                              void* d_out, int out_size, void* d_ws, size_t ws_size,
                              hipStream_t stream) {
    const float* feature   = (const float*)d_in[0];
    const float* keypoints = (const float*)d_in[1];
    float* out = (float*)d_out;

    const int grid = BB * (CC / CPT) * (NKP / 256);  // 2048
    interp_kernel<<<grid, 256, 0, stream>>>(feature, keypoints, out);
}